// Round 11
// baseline (181.154 us; speedup 1.0000x reference)
//
#include <hip/hip_runtime.h>
#include <hip/hip_bf16.h>
#include <cstddef>

#define P_ 2048
#define B_ 16
#define E_ 1024
#define D_ 128
#define L_ 16
#define TD_ 384

typedef _Float16 f16x2 __attribute__((ext_vector_type(2)));
typedef _Float16 f16x8 __attribute__((ext_vector_type(8)));
typedef float    f32x4 __attribute__((ext_vector_type(4)));

__device__ __forceinline__ unsigned short f2h(float x) {
    _Float16 h = (_Float16)x;
    return __builtin_bit_cast(unsigned short, h);
}
__device__ __forceinline__ unsigned pk2(float a, float b) {
    return __builtin_bit_cast(unsigned, __builtin_amdgcn_cvt_pkrtz(a, b));
}
__device__ __forceinline__ float lo16(unsigned u) {
    return (float)__builtin_bit_cast(f16x2, u)[0];
}
__device__ __forceinline__ float hi16(unsigned u) {
    return (float)__builtin_bit_cast(f16x2, u)[1];
}
__device__ __forceinline__ float dot2w(unsigned hu, unsigned qu, float c) {
#if __has_builtin(__builtin_amdgcn_fdot2)
    typedef __fp16 h2v __attribute__((ext_vector_type(2)));
    return __builtin_amdgcn_fdot2(__builtin_bit_cast(h2v, hu),
                                  __builtin_bit_cast(h2v, qu), c, false);
#else
    f16x2 h = __builtin_bit_cast(f16x2, hu), q = __builtin_bit_cast(f16x2, qu);
    return c + (float)h[0] * (float)q[0] + (float)h[1] * (float)q[1];
#endif
}

// ---- swizzle A: frag -> A[m][k] = src^T[m][k]  (also usable as B[k][n]=src[k][n])
__device__ __forceinline__ void wf16(const float* __restrict__ src,
                                     unsigned short* __restrict__ dst, int g, int N) {
    int lane = g & 63, kt = (g >> 6) & 3, tile = g >> 8;
    int k0 = kt * 32 + (lane >> 4) * 8;
    int c = tile * 16 + (lane & 15);
#pragma unroll
    for (int j = 0; j < 8; ++j)
        dst[(size_t)g * 8 + j] = f2h(src[(size_t)(k0 + j) * N + c]);
}
// ---- swizzle A non-transposed: frag -> A[m][k] = src[m][k] (src 128x128, row-contig)
__device__ __forceinline__ void wfT16(const float* __restrict__ src,
                                      unsigned short* __restrict__ dst, int g) {
    int lane = g & 63, kt = (g >> 6) & 3, tile = g >> 8;
    int k0 = kt * 32 + (lane >> 4) * 8;
    int m = tile * 16 + (lane & 15);
#pragma unroll
    for (int j = 0; j < 8; ++j)
        dst[(size_t)g * 8 + j] = f2h(src[(size_t)m * 128 + k0 + j]);
}

// ---- k_prep: pt init + all swizzles; 200 trivial blocks, no LDS -----------
// [0,128) pt=E_ | [128,152) WfR | [152,176) WfI | [176,184) wqf | [184,192) wkTf | [192,200) wvf
__global__ __launch_bounds__(256) void k_prep(const float* __restrict__ W_rec,
                                              const float* __restrict__ W_in,
                                              const float* __restrict__ wq,
                                              const float* __restrict__ wk,
                                              const float* __restrict__ wv,
                                              int* __restrict__ pt,
                                              unsigned short* __restrict__ WfR,
                                              unsigned short* __restrict__ WfI,
                                              unsigned short* __restrict__ wqf,
                                              unsigned short* __restrict__ wkTf,
                                              unsigned short* __restrict__ wvf) {
    int blk = blockIdx.x, tid = threadIdx.x;
    if      (blk < 128) pt[blk * 256 + tid] = E_;
    else if (blk < 152) wf16(W_rec, WfR, (blk - 128) * 256 + tid, TD_);
    else if (blk < 176) wf16(W_in,  WfI, (blk - 152) * 256 + tid, TD_);
    else if (blk < 184) wf16(wq,    wqf, (blk - 176) * 256 + tid, 128);
    else if (blk < 192) wfT16(wk,  wkTf, (blk - 184) * 256 + tid);
    else                wf16(wv,    wvf, (blk - 192) * 256 + tid, 128);
}

// ---- k_G (transposed MFMA): G2[b*1025+e][col]{z+bz+rz, r+br+rr, xh+bh, 0} --
// 256 thr / 4 waves; wave w: cols [32w,32w+32); lane (q,l15): row l15,
// col groups 32w+16ct+4q..+3 — coalesced dwordx4 stores.
// tails: pt scatter + sentinel rows
__global__ __launch_bounds__(256) void k_G(const float* __restrict__ inputs,
                                           const unsigned short* __restrict__ WfI,
                                           const float* __restrict__ b_in,
                                           const float* __restrict__ b_rec,
                                           unsigned short* __restrict__ G2,
                                           const int* __restrict__ paths,
                                           const int* __restrict__ idx,
                                           const int* __restrict__ seqs, int J, int scatB,
                                           int* __restrict__ pt) {
    if (blockIdx.x >= 1024) {
        int tb = blockIdx.x - 1024;
        if (tb < scatB) {
            int j = tb * 256 + threadIdx.x;
            if (j < J) pt[idx[j] * L_ + seqs[j]] = paths[j];
        } else {
            // sentinel rows: padded steps read x = 0 -> biases only
            for (int i = threadIdx.x; i < 2048; i += 256) {
                int bx = i >> 7, cc = i & 127;
                size_t base = ((size_t)(bx * (E_ + 1) + E_) * 128 + cc) * 4;
                G2[base]     = f2h(b_in[cc] + b_rec[cc]);
                G2[base + 1] = f2h(b_in[128 + cc] + b_rec[128 + cc]);
                G2[base + 2] = f2h(b_in[256 + cc]);
                G2[base + 3] = 0;
            }
        }
        return;
    }
    __shared__ __align__(16) unsigned short a_lds[16][136];
    __shared__ float bz_l[128], br_l[128], bh_l[128];
    int tid = threadIdx.x, w = tid >> 6, L = tid & 63;
    int l15 = L & 15, q = L >> 4;
    int row0 = blockIdx.x * 16;
    int badd = row0 >> 10;
    {
        int r = tid >> 4, cc = (tid & 15) * 8;
        const float4* p = (const float4*)(inputs + (size_t)(row0 + r) * 128 + cc);
        float4 v0 = p[0], v1 = p[1];
        uint4 st;
        st.x = pk2(v0.x, v0.y); st.y = pk2(v0.z, v0.w);
        st.z = pk2(v1.x, v1.y); st.w = pk2(v1.z, v1.w);
        *(uint4*)&a_lds[r][cc] = st;
    }
    if (tid < 128) {
        bz_l[tid] = b_in[tid] + b_rec[tid];
        br_l[tid] = b_in[128 + tid] + b_rec[128 + tid];
        bh_l[tid] = b_in[256 + tid];
    }
    __syncthreads();

    // B-fragments: x^T (B[k=din][n=row])
    f16x8 bf[4];
#pragma unroll
    for (int kt = 0; kt < 4; ++kt)
        bf[kt] = *(const f16x8*)&a_lds[l15][kt * 32 + q * 8];

    size_t rowbase = (size_t)(row0 + l15 + badd) * 1024;
#pragma unroll
    for (int ct = 0; ct < 2; ++ct) {
        int tz = 2 * w + ct, tr = 8 + 2 * w + ct, th = 16 + 2 * w + ct;
        f32x4 az = (f32x4){0.f,0.f,0.f,0.f}, ar = az, ah = az;
#pragma unroll
        for (int kt = 0; kt < 4; ++kt) {
            az = __builtin_amdgcn_mfma_f32_16x16x32_f16(
                *(const f16x8*)(WfI + (size_t)((tz * 4 + kt) * 64 + L) * 8), bf[kt], az, 0, 0, 0);
            ar = __builtin_amdgcn_mfma_f32_16x16x32_f16(
                *(const f16x8*)(WfI + (size_t)((tr * 4 + kt) * 64 + L) * 8), bf[kt], ar, 0, 0, 0);
            ah = __builtin_amdgcn_mfma_f32_16x16x32_f16(
                *(const f16x8*)(WfI + (size_t)((th * 4 + kt) * 64 + L) * 8), bf[kt], ah, 0, 0, 0);
        }
        int col0 = 32 * w + 16 * ct + 4 * q;
        uint4 s0, s1;
        s0.x = pk2(az[0] + bz_l[col0],     ar[0] + br_l[col0]);
        s0.y = pk2(ah[0] + bh_l[col0],     0.f);
        s0.z = pk2(az[1] + bz_l[col0 + 1], ar[1] + br_l[col0 + 1]);
        s0.w = pk2(ah[1] + bh_l[col0 + 1], 0.f);
        s1.x = pk2(az[2] + bz_l[col0 + 2], ar[2] + br_l[col0 + 2]);
        s1.y = pk2(ah[2] + bh_l[col0 + 2], 0.f);
        s1.z = pk2(az[3] + bz_l[col0 + 3], ar[3] + br_l[col0 + 3]);
        s1.w = pk2(ah[3] + bh_l[col0 + 3], 0.f);
        char* gp = (char*)G2 + rowbase + (size_t)col0 * 8;
        *(uint4*)gp = s0;
        *(uint4*)(gp + 16) = s1;
    }
}

// ---- fused GRU + attention (recurrence loop identical to round 10) --------
__global__ __launch_bounds__(512, 4) void k_rec(const unsigned short* __restrict__ WfR,
                                                const float* __restrict__ b_rec,
                                                const unsigned short* __restrict__ G2,
                                                const int* __restrict__ pt,
                                                const unsigned short* __restrict__ wqf,
                                                const unsigned short* __restrict__ wkTf,
                                                const unsigned short* __restrict__ wvf,
                                                float* __restrict__ out) {
    __shared__ __align__(16) unsigned short hsl[16][16][136];   // 69632 B
    __shared__ __align__(16) unsigned short qkb[16][136];       // 4352 B
    __shared__ __align__(16) unsigned short svb[16][136];       // 4352 B
    __shared__ float attp[2][16][16];                           // 2048 B
    __shared__ int ofs_lds[16][16];                             // 1024 B

    int tid = threadIdx.x, w = tid >> 6, L = tid & 63;
    int l15 = L & 15, q = L >> 4;
    int c0 = 16 * w + 4 * q;
    int n0 = blockIdx.x * 16;
    int b  = n0 >> 11;
    int p0 = n0 & (P_ - 1);
    int bb = b * (E_ + 1);

    f16x8 afw[3][4];
#pragma unroll
    for (int g = 0; g < 3; ++g)
#pragma unroll
        for (int kt = 0; kt < 4; ++kt)
            afw[g][kt] = *(const f16x8*)(WfR + (size_t)(((g * 8 + w) * 4 + kt) * 64 + L) * 8);

    if (tid < 256)
        ofs_lds[tid >> 4][tid & 15] = (bb + pt[p0 * L_ + tid]) << 10;

    f32x4 rh4;
#pragma unroll
    for (int j = 0; j < 4; ++j) rh4[j] = b_rec[256 + c0 + j];
    float h_reg[4] = {0.f, 0.f, 0.f, 0.f};
    __syncthreads();

    int ofs[16];
    {
        const uint4* op = (const uint4*)&ofs_lds[l15][0];
        uint4 o0 = op[0], o1 = op[1], o2 = op[2], o3 = op[3];
        ofs[0]  = o0.x; ofs[1]  = o0.y; ofs[2]  = o0.z; ofs[3]  = o0.w;
        ofs[4]  = o1.x; ofs[5]  = o1.y; ofs[6]  = o1.z; ofs[7]  = o1.w;
        ofs[8]  = o2.x; ofs[9]  = o2.y; ofs[10] = o2.z; ofs[11] = o2.w;
        ofs[12] = o3.x; ofs[13] = o3.y; ofs[14] = o3.z; ofs[15] = o3.w;
    }

    const char* g2c = (const char*)G2 + (size_t)c0 * 8;
    uint4 cur0 = *(const uint4*)(g2c + ofs[0]);
    uint4 cur1 = *(const uint4*)(g2c + ofs[0] + 16);

#pragma unroll
    for (int t = 0; t < L_; ++t) {
        uint4 nx0 = cur0, nx1 = cur1;
        if (t < 15) {
            const char* gp = g2c + ofs[t + 1];
            nx0 = *(const uint4*)(gp);
            nx1 = *(const uint4*)(gp + 16);
        }

        float xh[4];
        f32x4 acc[3];
        acc[0][0] = lo16(cur0.x); acc[0][1] = lo16(cur0.z);
        acc[0][2] = lo16(cur1.x); acc[0][3] = lo16(cur1.z);
        acc[1][0] = hi16(cur0.x); acc[1][1] = hi16(cur0.z);
        acc[1][2] = hi16(cur1.x); acc[1][3] = hi16(cur1.z);
        xh[0] = lo16(cur0.y); xh[1] = lo16(cur0.w);
        xh[2] = lo16(cur1.y); xh[3] = lo16(cur1.w);
        acc[2] = rh4;

        if (t > 0) {
            f16x8 hf[4];
#pragma unroll
            for (int kt = 0; kt < 4; ++kt)
                hf[kt] = *(const f16x8*)&hsl[t - 1][l15][kt * 32 + q * 8];
#pragma unroll
            for (int g = 0; g < 3; ++g)
#pragma unroll
                for (int kt = 0; kt < 4; ++kt)
                    acc[g] = __builtin_amdgcn_mfma_f32_16x16x32_f16(afw[g][kt], hf[kt], acc[g], 0, 0, 0);
        }

        float hn[4];
#pragma unroll
        for (int j = 0; j < 4; ++j) {
            float z   = __builtin_amdgcn_rcpf(1.f + __expf(-acc[0][j]));
            float rg  = __builtin_amdgcn_rcpf(1.f + __expf(-acc[1][j]));
            float pre = xh[j] + rg * acc[2][j];
            float hc  = 1.f - 2.f * __builtin_amdgcn_rcpf(__expf(2.f * pre) + 1.f);
            hn[j] = hc + z * (h_reg[j] - hc);
            h_reg[j] = hn[j];
        }
        uint2 st;
        st.x = pk2(hn[0], hn[1]); st.y = pk2(hn[2], hn[3]);
        *(uint2*)&hsl[t][l15][c0] = st;
        cur0 = nx0; cur1 = nx1;

        __builtin_amdgcn_wave_barrier();
        __builtin_amdgcn_s_waitcnt(0xC07F);   // lgkmcnt(0) only
        __builtin_amdgcn_s_barrier();
        __builtin_amdgcn_wave_barrier();
    }

    // ===== attention =====
    // u^T = (wq^T)(last^T) -> svb
    {
        f16x8 hf[4];
#pragma unroll
        for (int kt = 0; kt < 4; ++kt)
            hf[kt] = *(const f16x8*)&hsl[15][l15][kt * 32 + q * 8];
        f32x4 a = (f32x4){0.f, 0.f, 0.f, 0.f};
#pragma unroll
        for (int kt = 0; kt < 4; ++kt)
            a = __builtin_amdgcn_mfma_f32_16x16x32_f16(
                *(const f16x8*)(wqf + (size_t)((w * 4 + kt) * 64 + L) * 8), hf[kt], a, 0, 0, 0);
        uint2 st;
        st.x = pk2(a[0], a[1]); st.y = pk2(a[2], a[3]);
        *(uint2*)&svb[l15][c0] = st;
    }
    __syncthreads();

    // qk^T = (wk)(u^T) -> qkb
    {
        f16x8 uf[4];
#pragma unroll
        for (int kt = 0; kt < 4; ++kt)
            uf[kt] = *(const f16x8*)&svb[l15][kt * 32 + q * 8];
        f32x4 a = (f32x4){0.f, 0.f, 0.f, 0.f};
#pragma unroll
        for (int kt = 0; kt < 4; ++kt)
            a = __builtin_amdgcn_mfma_f32_16x16x32_f16(
                *(const f16x8*)(wkTf + (size_t)((w * 4 + kt) * 64 + L) * 8), uf[kt], a, 0, 0, 0);
        uint2 st;
        st.x = pk2(a[0], a[1]); st.y = pk2(a[2], a[3]);
        *(uint2*)&qkb[l15][c0] = st;
    }
    __syncthreads();

    // att partials: all 512 threads; half = k-range
    {
        int s = tid & 15, l = (tid >> 4) & 15, half = tid >> 8;
        const uint4* hr = (const uint4*)&hsl[l][s][half * 64];
        const uint4* qr = (const uint4*)&qkb[s][half * 64];
        float a = 0.f;
#pragma unroll
        for (int k8 = 0; k8 < 8; ++k8) {
            uint4 hh = hr[k8], qq = qr[k8];
            a = dot2w(hh.x, qq.x, a); a = dot2w(hh.y, qq.y, a);
            a = dot2w(hh.z, qq.z, a); a = dot2w(hh.w, qq.w, a);
        }
        attp[half][s][l] = a;
    }
    __syncthreads();

    // svec -> svb
    {
        int s = tid >> 5, d0 = (tid & 31) * 4;
        float v[4] = {0.f, 0.f, 0.f, 0.f};
#pragma unroll
        for (int l = 0; l < 16; ++l) {
            float a = attp[0][s][l] + attp[1][s][l];
            uint2 hu = *(const uint2*)&hsl[l][s][d0];
            v[0] += a * lo16(hu.x); v[1] += a * hi16(hu.x);
            v[2] += a * lo16(hu.y); v[3] += a * hi16(hu.y);
        }
        uint2 st;
        st.x = pk2(v[0], v[1]); st.y = pk2(v[2], v[3]);
        *(uint2*)&svb[s][d0] = st;
    }
    __syncthreads();

    // ctx^T = (wv^T)(svec^T) -> out
    {
        f16x8 sf[4];
#pragma unroll
        for (int kt = 0; kt < 4; ++kt)
            sf[kt] = *(const f16x8*)&svb[l15][kt * 32 + q * 8];
        f32x4 a = (f32x4){0.f, 0.f, 0.f, 0.f};
#pragma unroll
        for (int kt = 0; kt < 4; ++kt)
            a = __builtin_amdgcn_mfma_f32_16x16x32_f16(
                *(const f16x8*)(wvf + (size_t)((w * 4 + kt) * 64 + L) * 8), sf[kt], a, 0, 0, 0);
        *(f32x4*)&out[(size_t)(n0 + l15) * D_ + c0] = a;
    }
}

// ---------------------------------------------------------------------------
extern "C" void kernel_launch(void* const* d_in, const int* in_sizes, int n_in,
                              void* d_out, int out_size, void* d_ws, size_t ws_size,
                              hipStream_t stream) {
    const float* inputs = (const float*)d_in[0];
    const float* W_in   = (const float*)d_in[1];
    const float* W_rec  = (const float*)d_in[2];
    const float* b_in   = (const float*)d_in[3];
    const float* b_rec  = (const float*)d_in[4];
    const float* wq     = (const float*)d_in[5];
    const float* wk     = (const float*)d_in[6];
    const float* wvp    = (const float*)d_in[7];
    const int* paths    = (const int*)d_in[8];
    const int* idx      = (const int*)d_in[9];
    const int* seqs     = (const int*)d_in[10];
    int J = in_sizes[8];

    // ws layout (bytes): ~17.2 MiB
    const size_t off_pt   = 0;
    const size_t off_WfR  = off_pt   + (size_t)P_ * L_ * 4;       // 131072
    const size_t off_WfI  = off_WfR  + (size_t)24 * 256 * 16;     // +98304
    const size_t off_wqf  = off_WfI  + (size_t)24 * 256 * 16;     // +98304
    const size_t off_wkTf = off_wqf  + (size_t)8 * 256 * 16;      // +32768
    const size_t off_wvf  = off_wkTf + (size_t)8 * 256 * 16;      // +32768
    const size_t off_G2   = off_wvf  + (size_t)8 * 256 * 16;      // +32768
    // G2: 16 * 1025 * 128 * 4 u16 = 16,793,600 B
    char* ws = (char*)d_ws;
    int* pt              = (int*)(ws + off_pt);
    unsigned short* WfR  = (unsigned short*)(ws + off_WfR);
    unsigned short* WfI  = (unsigned short*)(ws + off_WfI);
    unsigned short* wqf  = (unsigned short*)(ws + off_wqf);
    unsigned short* wkTf = (unsigned short*)(ws + off_wkTf);
    unsigned short* wvf  = (unsigned short*)(ws + off_wvf);
    unsigned short* G2   = (unsigned short*)(ws + off_G2);
    float* out = (float*)d_out;

    int scatB = (J + 255) / 256;
    k_prep<<<dim3(200), dim3(256), 0, stream>>>(W_rec, W_in, wq, wk, wvp, pt,
                                                WfR, WfI, wqf, wkTf, wvf);
    k_G<<<dim3(1024 + scatB + 1), dim3(256), 0, stream>>>(inputs, WfI, b_in, b_rec,
                                                          G2, paths, idx, seqs, J,
                                                          scatB, pt);
    k_rec<<<dim3(B_ * P_ / 16), dim3(512), 0, stream>>>(WfR, b_rec, G2, pt,
                                                        wqf, wkTf, wvf, out);
}